// Round 2
// baseline (718.142 us; speedup 1.0000x reference)
//
#include <hip/hip_runtime.h>

typedef unsigned short u16;
typedef __attribute__((ext_vector_type(8))) short  s16x8;
typedef __attribute__((ext_vector_type(8))) u16    u16x8;
typedef __attribute__((ext_vector_type(4))) float  f32x4;

#define NB    8
#define HH    56
#define WWI   56
#define CDIM  512
#define CQKV  1536
#define P2C   49
#define NROWS (NB*P2C*64)      // 25088 windowed pixel rows
#define SCALE_F 0.04419417382415922f

__device__ __forceinline__ u16 f2bf(float f) {
  union { float f; unsigned u; } x; x.f = f;
  unsigned r = x.u + 0x7fffu + ((x.u >> 16) & 1u);
  return (u16)(r >> 16);
}
__device__ __forceinline__ float bf2f(u16 h) {
  union { unsigned u; float f; } x; x.u = ((unsigned)h) << 16;
  return x.f;
}

__device__ __forceinline__ void gld16(const void* g, void* l) {
  __builtin_amdgcn_global_load_lds((const __attribute__((address_space(1))) void*)g,
                                   (__attribute__((address_space(3))) void*)l, 16, 0, 0);
}

// ---- weight prep: [rows][512] f32 -> [rows][1536] bf16 = [hi | hi | lo] ----
__global__ __launch_bounds__(256) void k_prep_b(const float* __restrict__ w, u16* __restrict__ Bq) {
  int t = blockIdx.x * 256 + threadIdx.x;
  int r = t >> 6, c8 = (t & 63) << 3;
  const float* src = w + (size_t)r * CDIM + c8;
  float4 v0 = *(const float4*)src, v1 = *(const float4*)(src + 4);
  float vv[8] = {v0.x, v0.y, v0.z, v0.w, v1.x, v1.y, v1.z, v1.w};
  u16x8 Hh, Ll;
#pragma unroll
  for (int i = 0; i < 8; i++) {
    u16 h = f2bf(vv[i]); Hh[i] = h; Ll[i] = f2bf(vv[i] - bf2f(h));
  }
  u16* dst = Bq + (size_t)r * CQKV;
  *(u16x8*)(dst + c8)        = Hh;
  *(u16x8*)(dst + 512 + c8)  = Hh;
  *(u16x8*)(dst + 1024 + c8) = Ll;
}

// ---- GEMM1: qkv = window(x) @ qkv_w^T + b, split-bf16 K=1536, A reg-staged from f32 x.
//      Epilogue: qkvh bf16 [25088][1536]; window means (f32, from accumulators) -> qw,kw.
__global__ __launch_bounds__(256) void k_gemm1(const float* __restrict__ X, const u16* __restrict__ B,
                                               const float* __restrict__ bias,
                                               u16* __restrict__ qkvh, float* __restrict__ qw,
                                               float* __restrict__ kw) {
  __shared__ u16 As[128 * 32];
  __shared__ u16 Bs[128 * 32];
  const int K = CQKV;
  int bx = blockIdx.x % 12, by = blockIdx.x / 12;
  int tid = threadIdx.x, lane = tid & 63, wid = tid >> 6;
  int wr = (wid >> 1) << 6, wc = (wid & 1) << 6;
  int l15 = lane & 15, h4 = lane >> 4;
  // A source: row mapping (windowed) fixed per thread
  int arow = tid >> 1;            // 0..127
  int acol0 = (tid & 1) << 4;     // 0 or 16
  int grow = (by << 7) + arow;
  int n = grow / (P2C * 64); int rem = grow - n * (P2C * 64);
  int p = rem >> 6, pix = rem & 63;
  int y = (p / 7) * 8 + (pix >> 3), xx = (p % 7) * 8 + (pix & 7);
  const float* xrow = X + ((size_t)((n * HH + y) * WWI + xx)) * CDIM;
  u16* awr = (u16*)((char*)As + arow * 64 + acol0 * 2);
  // B staging indices
  int br0 = tid >> 2, bc0 = (tid & 3) << 3;
  const u16* Bb = B + (size_t)(bx << 7) * K;
  f32x4 acc[4][4] = {};
  for (int k0 = 0; k0 < K; k0 += 32) {
    gld16(Bb + (size_t)br0 * K + k0 + bc0,        (char*)Bs + tid * 16);
    gld16(Bb + (size_t)(br0 + 64) * K + k0 + bc0, (char*)Bs + 4096 + tid * 16);
    int c0 = (k0 < 512) ? k0 : (k0 < 1024 ? k0 - 512 : k0 - 1024);
    int islo = (k0 >= 512) && (k0 < 1024);
    const float* src = xrow + c0 + acol0;
    float4 v0 = *(const float4*)src,      v1 = *(const float4*)(src + 4),
           v2 = *(const float4*)(src + 8), v3 = *(const float4*)(src + 12);
    float vv[16] = {v0.x, v0.y, v0.z, v0.w, v1.x, v1.y, v1.z, v1.w,
                    v2.x, v2.y, v2.z, v2.w, v3.x, v3.y, v3.z, v3.w};
    u16x8 o0, o1;
    if (islo) {
#pragma unroll
      for (int i = 0; i < 8; i++) {
        o0[i] = f2bf(vv[i]     - bf2f(f2bf(vv[i])));
        o1[i] = f2bf(vv[8 + i] - bf2f(f2bf(vv[8 + i])));
      }
    } else {
#pragma unroll
      for (int i = 0; i < 8; i++) { o0[i] = f2bf(vv[i]); o1[i] = f2bf(vv[8 + i]); }
    }
    *(u16x8*)awr = o0;
    *(u16x8*)(awr + 8) = o1;
    __syncthreads();
    s16x8 af[4], bfr[4];
#pragma unroll
    for (int f = 0; f < 4; f++) af[f]  = *(const s16x8*)((const char*)As + (wr + f * 16 + l15) * 64 + h4 * 16);
#pragma unroll
    for (int f = 0; f < 4; f++) bfr[f] = *(const s16x8*)((const char*)Bs + (wc + f * 16 + l15) * 64 + h4 * 16);
#pragma unroll
    for (int i = 0; i < 4; i++)
#pragma unroll
      for (int j = 0; j < 4; j++)
        acc[i][j] = __builtin_amdgcn_mfma_f32_16x16x32_bf16(af[i], bfr[j], acc[i][j], 0, 0, 0);
    __syncthreads();
  }
  // epilogue: bf16 store + window means
#pragma unroll
  for (int i = 0; i < 4; i++) {
#pragma unroll
    for (int j = 0; j < 4; j++) {
      int col = (bx << 7) + wc + j * 16 + l15;
      float bcol = bias[col];
#pragma unroll
      for (int rg = 0; rg < 4; rg++) {
        int row = (by << 7) + wr + i * 16 + h4 * 4 + rg;
        qkvh[(size_t)row * CQKV + col] = f2bf(acc[i][j][rg] + bcol);
      }
    }
  }
  int np = (by << 1) + (wr >> 6);   // this wave's window
#pragma unroll
  for (int j = 0; j < 4; j++) {
    float s = 0.f;
#pragma unroll
    for (int i = 0; i < 4; i++)
#pragma unroll
      for (int rg = 0; rg < 4; rg++) s += acc[i][j][rg];
    s += __shfl_xor(s, 16);
    s += __shfl_xor(s, 32);
    int col = (bx << 7) + wc + j * 16 + l15;
    if (h4 == 0 && col < 1024) {
      float mv = s * (1.f / 64.f) + bias[col];
      if (col < 512) qw[(size_t)np * 512 + col] = mv;
      else           kw[(size_t)np * 512 + (col - 512)] = mv;
    }
  }
}

// ---- generic bf16 GEMM (GEMM2), C = A(MxK)*B(NxK)^T + bias; unwin epilogue layout ----
__global__ __launch_bounds__(256) void k_gemm(const u16* __restrict__ A, const u16* __restrict__ B,
                                              float* __restrict__ C, const float* __restrict__ bias,
                                              int M, int N, int K, int unwin) {
  __shared__ u16 As[128 * 32];
  __shared__ u16 Bs[128 * 32];
  int nbn = N >> 7;
  int bx = blockIdx.x % nbn, by = blockIdx.x / nbn;
  int tid = threadIdx.x, lane = tid & 63, wid = tid >> 6;
  int wr = (wid >> 1) << 6, wc = (wid & 1) << 6;
  int l15 = lane & 15, h4 = lane >> 4;
  int ar0 = tid >> 2, ac0 = (tid & 3) << 3;
  const u16* Ab = A + (size_t)(by << 7) * K;
  const u16* Bb = B + (size_t)(bx << 7) * K;
  f32x4 acc[4][4] = {};
  for (int k0 = 0; k0 < K; k0 += 32) {
    gld16(Ab + (size_t)ar0 * K + k0 + ac0,        (char*)As + tid * 16);
    gld16(Ab + (size_t)(ar0 + 64) * K + k0 + ac0, (char*)As + 4096 + tid * 16);
    gld16(Bb + (size_t)ar0 * K + k0 + ac0,        (char*)Bs + tid * 16);
    gld16(Bb + (size_t)(ar0 + 64) * K + k0 + ac0, (char*)Bs + 4096 + tid * 16);
    __syncthreads();
    s16x8 af[4], bfr[4];
#pragma unroll
    for (int f = 0; f < 4; f++) af[f]  = *(const s16x8*)((const char*)As + (wr + f * 16 + l15) * 64 + h4 * 16);
#pragma unroll
    for (int f = 0; f < 4; f++) bfr[f] = *(const s16x8*)((const char*)Bs + (wc + f * 16 + l15) * 64 + h4 * 16);
#pragma unroll
    for (int i = 0; i < 4; i++)
#pragma unroll
      for (int j = 0; j < 4; j++)
        acc[i][j] = __builtin_amdgcn_mfma_f32_16x16x32_bf16(af[i], bfr[j], acc[i][j], 0, 0, 0);
    __syncthreads();
  }
#pragma unroll
  for (int i = 0; i < 4; i++) {
#pragma unroll
    for (int j = 0; j < 4; j++) {
      int col = (bx << 7) + wc + j * 16 + l15;
      float bcol = bias[col];
#pragma unroll
      for (int rg = 0; rg < 4; rg++) {
        int row = (by << 7) + wr + i * 16 + h4 * 4 + rg;
        float v = acc[i][j][rg] + bcol;
        size_t idx;
        if (!unwin) idx = (size_t)row * N + col;
        else {
          int n = row / (P2C * 64); int rem = row - n * (P2C * 64);
          int p = rem >> 6, pix = rem & 63;
          int y = (p / 7) * 8 + (pix >> 3), xx = (p % 7) * 8 + (pix & 7);
          idx = (size_t)((n * HH + y) * WWI + xx) * N + col;
        }
        C[idx] = v;
      }
    }
  }
}

// ---- routing: per (n,p) 49 logits from f32 window means, top-4 (stable ties) ----
__global__ __launch_bounds__(64) void k_route(const float* __restrict__ qw,
                                              const float* __restrict__ kw, int* __restrict__ ridx) {
  int np = blockIdx.x, n = np / P2C;
  int t = threadIdx.x;
  __shared__ float qrow[512];
  __shared__ float logit[64];
  for (int c = t; c < 512; c += 64) qrow[c] = qw[(size_t)np * 512 + c];
  __syncthreads();
  if (t < P2C) {
    const float* kr = kw + (size_t)(n * P2C + t) * 512;
    float s = 0.f;
    for (int c = 0; c < 512; c++) s += qrow[c] * kr[c];
    logit[t] = s;
  }
  __syncthreads();
  if (t == 0) {
    for (int tt = 0; tt < 4; tt++) {
      float best = -1e30f; int bi = 0;
      for (int q = 0; q < P2C; q++) if (logit[q] > best) { best = logit[q]; bi = q; }
      ridx[np * 4 + tt] = bi;
      logit[bi] = -1e30f;
    }
  }
}

// ---- LePE depthwise 3x3 (zero pad) on v (bf16 in qkvh), bf16 out, windowed rows ----
__global__ __launch_bounds__(256) void k_lepe(const u16* __restrict__ qkvh,
                                              const float* __restrict__ lw, const float* __restrict__ lb,
                                              u16* __restrict__ lepe) {
  int t = blockIdx.x * 256 + threadIdx.x;
  int r = t >> 6, c8 = (t & 63) << 3;
  int n = r / (P2C * 64); int rem = r - n * (P2C * 64);
  int p = rem >> 6, pix = rem & 63;
  int y = (p / 7) * 8 + (pix >> 3), xx = (p % 7) * 8 + (pix & 7);
  float acc[8];
#pragma unroll
  for (int i = 0; i < 8; i++) acc[i] = lb[c8 + i];
#pragma unroll
  for (int dy = -1; dy <= 1; dy++) {
#pragma unroll
    for (int dx = -1; dx <= 1; dx++) {
      int yy = y + dy, xz = xx + dx;
      if (yy < 0 || yy >= HH || xz < 0 || xz >= WWI) continue;
      int p2 = (yy >> 3) * 7 + (xz >> 3), px2 = (yy & 7) * 8 + (xz & 7);
      const u16* v = qkvh + ((size_t)((n * P2C + p2) * 64 + px2)) * CQKV + 1024 + c8;
      u16x8 a = *(const u16x8*)v;
#pragma unroll
      for (int i = 0; i < 8; i++) acc[i] += bf2f(a[i]) * lw[(c8 + i) * 9 + (dy + 1) * 3 + (dx + 1)];
    }
  }
  u16x8 o;
#pragma unroll
  for (int i = 0; i < 8; i++) o[i] = f2bf(acc[i]);
  *(u16x8*)(lepe + (size_t)r * CDIM + c8) = o;
}

// ---- attention: block=(np, head-quad), wave=head. Swapped S^T=K*Q^T, in-reg softmax, PV.
//      Epilogue: + lepe, write split [hi|lo|hi] A2 operand for GEMM2.
__global__ __launch_bounds__(256) void k_attn(const u16* __restrict__ qkvh,
                                              const int* __restrict__ ridx,
                                              const u16* __restrict__ lepe, u16* __restrict__ A2) {
  int b = blockIdx.x;
  int mq = b & 3, np = b >> 2;
  int n = np / P2C;
  int wid = threadIdx.x >> 6, lane = threadIdx.x & 63;
  int m = (mq << 2) + wid;
  int l15 = lane & 15, h4 = lane >> 4;
  size_t krow0[4];
#pragma unroll
  for (int w = 0; w < 4; w++) krow0[w] = (size_t)(n * P2C + ridx[np * 4 + w]) * 64;
  size_t qrow0 = (size_t)np * 64;
  union FR { s16x8 s; u16 u[8]; };
  f32x4 zero = {0.f, 0.f, 0.f, 0.f};
  FR qf[4];
#pragma unroll
  for (int fq = 0; fq < 4; fq++)
    qf[fq].s = *(const s16x8*)(qkvh + (qrow0 + fq * 16 + l15) * CQKV + m * 32 + h4 * 8);
#pragma unroll
  for (int fq = 0; fq < 4; fq++) {
    f32x4 st[16];
#pragma unroll
    for (int fk = 0; fk < 16; fk++) {
      int key = fk * 16 + l15;
      FR kf;
      kf.s = *(const s16x8*)(qkvh + (krow0[key >> 6] + (key & 63)) * CQKV + 512 + m * 32 + h4 * 8);
      st[fk] = __builtin_amdgcn_mfma_f32_16x16x32_bf16(kf.s, qf[fq].s, zero, 0, 0, 0);
    }
    float mx = -1e30f;
#pragma unroll
    for (int fk = 0; fk < 16; fk++)
#pragma unroll
      for (int rg = 0; rg < 4; rg++) {
        float v = st[fk][rg] * SCALE_F; st[fk][rg] = v; mx = fmaxf(mx, v);
      }
    mx = fmaxf(mx, __shfl_xor(mx, 16));
    mx = fmaxf(mx, __shfl_xor(mx, 32));
    float sum = 0.f;
#pragma unroll
    for (int fk = 0; fk < 16; fk++)
#pragma unroll
      for (int rg = 0; rg < 4; rg++) {
        float e = __expf(st[fk][rg] - mx); st[fk][rg] = e; sum += e;
      }
    sum += __shfl_xor(sum, 16);
    sum += __shfl_xor(sum, 32);
    f32x4 oacc[2] = {zero, zero};
#pragma unroll
    for (int s8 = 0; s8 < 8; s8++) {
      FR pa;
#pragma unroll
      for (int jj = 0; jj < 8; jj++) pa.u[jj] = f2bf(st[2 * s8 + (jj >> 2)][jj & 3]);
#pragma unroll
      for (int fd = 0; fd < 2; fd++) {
        FR vf;
#pragma unroll
        for (int jj = 0; jj < 8; jj++) {
          int key = 32 * s8 + h4 * 4 + (jj & 3) + ((jj >> 2) << 4);
          vf.u[jj] = qkvh[(krow0[key >> 6] + (key & 63)) * CQKV + 1024 + m * 32 + fd * 16 + l15];
        }
        oacc[fd] = __builtin_amdgcn_mfma_f32_16x16x32_bf16(pa.s, vf.s, oacc[fd], 0, 0, 0);
      }
    }
#pragma unroll
    for (int rg = 0; rg < 4; rg++) {
      float sq = __shfl(sum, h4 * 4 + rg);
      int q = fq * 16 + h4 * 4 + rg;
#pragma unroll
      for (int fd = 0; fd < 2; fd++) {
        int col = m * 32 + fd * 16 + l15;
        size_t row = qrow0 + q;
        float val = oacc[fd][rg] / sq + bf2f(lepe[row * CDIM + col]);
        u16 hi = f2bf(val);
        u16 lo = f2bf(val - bf2f(hi));
        A2[row * CQKV + col]        = hi;
        A2[row * CQKV + 512 + col]  = lo;
        A2[row * CQKV + 1024 + col] = hi;
      }
    }
  }
}

extern "C" void kernel_launch(void* const* d_in, const int* in_sizes, int n_in,
                              void* d_out, int out_size, void* d_ws, size_t ws_size,
                              hipStream_t stream) {
  (void)in_sizes; (void)n_in; (void)out_size; (void)ws_size;
  const float* x      = (const float*)d_in[0];
  const float* qkv_w  = (const float*)d_in[1];
  const float* qkv_b  = (const float*)d_in[2];
  const float* wo_w   = (const float*)d_in[3];
  const float* wo_b   = (const float*)d_in[4];
  const float* lepe_w = (const float*)d_in[5];
  const float* lepe_b = (const float*)d_in[6];
  float* out = (float*)d_out;
  char* ws = (char*)d_ws;
  size_t off = 0;
  auto alc = [&](size_t b) { char* p = ws + off; off += (b + 255) & ~(size_t)255; return p; };
  u16*   B1    = (u16*)  alc((size_t)CQKV * CQKV * 2);        //  4.7 MB
  u16*   B2    = (u16*)  alc((size_t)CDIM * CQKV * 2);        //  1.6 MB
  u16*   qkvh  = (u16*)  alc((size_t)NROWS * CQKV * 2);       // 77.1 MB
  float* qw    = (float*)alc((size_t)NB * P2C * CDIM * 4);    //  0.8 MB
  float* kw    = (float*)alc((size_t)NB * P2C * CDIM * 4);    //  0.8 MB
  int*   ridx  = (int*)  alc((size_t)NB * P2C * 4 * 4);       //  6 KB
  u16*   lepe  = (u16*)  alc((size_t)NROWS * CDIM * 2);       // 25.7 MB
  u16*   A2    = (u16*)  alc((size_t)NROWS * CQKV * 2);       // 77.1 MB
  // total ~188 MB

  k_prep_b<<<dim3(384),  dim3(256), 0, stream>>>(qkv_w, B1);
  k_prep_b<<<dim3(128),  dim3(256), 0, stream>>>(wo_w, B2);
  k_gemm1 <<<dim3(2352), dim3(256), 0, stream>>>(x, B1, qkv_b, qkvh, qw, kw);
  k_route <<<dim3(392),  dim3(64),  0, stream>>>(qw, kw, ridx);
  k_lepe  <<<dim3(6272), dim3(256), 0, stream>>>(qkvh, lepe_w, lepe_b, lepe);
  k_attn  <<<dim3(1568), dim3(256), 0, stream>>>(qkvh, ridx, lepe, A2);
  k_gemm  <<<dim3(784),  dim3(256), 0, stream>>>(A2, B2, out, wo_b, NROWS, CDIM, CQKV, 1);
}